// Round 4
// baseline (293.263 us; speedup 1.0000x reference)
//
#include <hip/hip_runtime.h>

// PatchExtractor: crop-to-bbox central square + bilinear resize to 224x224 + CLIP normalize.
// img: [3,2048,2048] f32, bboxes: [N,4] i32 xyxy, out: [N,3,224,224] f32.
//
// R3: LDS row-staging. One block = one (box, output row). sy/iy0/iy1 are
// block-uniform -> stage the 2 needed source rows x 3 channels (span <= 320 px,
// 7.9 KB LDS) with cooperated coalesced loads, then all bilinear taps hit LDS
// (lane stride <= 1.43 words => <=2-3-way bank aliasing, ~free). Replaces the
// scattered 4B global gathers (L1-thrashing, ~0.9 GB L2/L3 line traffic) that
// made R2 latency-bound at 2 TB/s / 22% VALU. Plain coalesced dword stores
// (nt removed: coincided with R2 regression). 8 blocks/CU -> 100% occupancy.

#define S      224
#define IMG_H  2048
#define IMG_W  2048
#define PITCH  328            // max span 320, padded; %4==0

__global__ __launch_bounds__(256) void patch_kernel(
    const float* __restrict__ img,
    const float* __restrict__ mean,
    const float* __restrict__ stdd,
    const int*   __restrict__ bboxes,
    float*       __restrict__ out)
{
    const int n  = blockIdx.y;    // box
    const int oy = blockIdx.x;    // output row
    const int tid = threadIdx.x;

    __shared__ float lds[6][PITCH];   // [row(0=iy0,1=iy1)*3 + c][x - ix_lo]

    // bbox math (block-uniform)
    const float x0 = (float)bboxes[n * 4 + 0];
    const float y0 = (float)bboxes[n * 4 + 1];
    const float x1 = (float)bboxes[n * 4 + 2];
    const float y1 = (float)bboxes[n * 4 + 3];
    const float side  = fminf(x1 - x0, y1 - y0);
    const float basex = (x0 + x1) * 0.5f - side * 0.5f - 0.5f;
    const float basey = (y0 + y1) * 0.5f - side * 0.5f - 0.5f;
    const float invS  = 1.0f / (float)S;

    // vertical (uniform): geometry guarantees 0 <= sy <= 2046.5
    float sy = fmaf((oy + 0.5f) * invS, side, basey);
    sy = fminf(fmaxf(sy, 0.0f), (float)(IMG_H - 1));
    const int   iy0 = (int)floorf(sy);
    const int   iy1 = min(iy0 + 1, IMG_H - 1);
    const float wy  = sy - (float)iy0;

    // horizontal span (uniform): sx is monotone in ox, so all taps lie in
    // [ix_lo, ix_hi]. Use the IDENTICAL per-pixel formula for the endpoints.
    float sx_first = fmaf((0   + 0.5f) * invS, side, basex);
    float sx_last  = fmaf((223 + 0.5f) * invS, side, basex);
    sx_first = fminf(fmaxf(sx_first, 0.0f), (float)(IMG_W - 1));
    sx_last  = fminf(fmaxf(sx_last,  0.0f), (float)(IMG_W - 1));
    const int ix_lo = (int)floorf(sx_first);
    const int ix_hi = min((int)floorf(sx_last) + 1, IMG_W - 1);
    const int L     = ix_hi - ix_lo + 1;          // <= 320

    // stage 6 rows (2 source rows x 3 channels), coalesced contiguous
    for (int rc = 0; rc < 6; ++rc) {
        const int r = (rc < 3) ? iy0 : iy1;
        const int c = (rc < 3) ? rc  : rc - 3;
        const float* __restrict__ src =
            img + (size_t)c * (IMG_H * IMG_W) + (size_t)r * IMG_W + ix_lo;
        for (int off = tid; off < L; off += 256)
            lds[rc][off] = src[off];
    }
    __syncthreads();

    // 672 outputs (3 ch x 224 px), <=3 iterations/thread
    for (int k = tid; k < 3 * S; k += 256) {
        const int c  = k / S;
        const int ox = k - c * S;

        float sx = fmaf((ox + 0.5f) * invS, side, basex);
        sx = fminf(fmaxf(sx, 0.0f), (float)(IMG_W - 1));
        const int   ix = (int)floorf(sx);
        const float wx = sx - (float)ix;
        const int   o0 = ix - ix_lo;              // [0, L-2]

        const float* row0 = lds[c];
        const float* row1 = lds[3 + c];
        const float p00 = row0[o0], p01 = row0[o0 + 1];
        const float p10 = row1[o0], p11 = row1[o0 + 1];
        const float top = fmaf(wx, p01 - p00, p00);
        const float bot = fmaf(wx, p11 - p10, p10);
        const float v   = fmaf(wy, bot - top, top);

        const float sd = stdd[c];
        const float o  = fmaf(v, 1.0f / (255.0f * sd), -mean[c] / sd);
        out[((size_t)(n * 3 + c) * S + (size_t)oy) * S + ox] = o;
    }
}

extern "C" void kernel_launch(void* const* d_in, const int* in_sizes, int n_in,
                              void* d_out, int out_size, void* d_ws, size_t ws_size,
                              hipStream_t stream)
{
    const float* img    = (const float*)d_in[0];
    const float* mean   = (const float*)d_in[1];
    const float* stdd   = (const float*)d_in[2];
    const int*   bboxes = (const int*)d_in[3];
    float* out = (float*)d_out;

    const int N = in_sizes[3] / 4;        // 256 boxes
    dim3 grid(S, N);                      // 224 rows x 256 boxes
    patch_kernel<<<grid, 256, 0, stream>>>(img, mean, stdd, bboxes, out);
}